// Round 1
// baseline (1332.361 us; speedup 1.0000x reference)
//
#include <hip/hip_runtime.h>
#include <hip/hip_bf16.h>

typedef unsigned short ushort_t;
typedef __attribute__((ext_vector_type(8))) short short8;
typedef __attribute__((ext_vector_type(4))) float f32x4;

#define DI __device__ __forceinline__

DI float b2f(unsigned int u16) {
  union { unsigned int i; float f; } v;
  v.i = u16 << 16;
  return v.f;
}
DI ushort_t f2b(float f) {
  union { float f; unsigned int u; } v; v.f = f;
  unsigned int r = v.u + 0x7FFFu + ((v.u >> 16) & 1u);
  return (ushort_t)(r >> 16);
}

// ---------------------------------------------------------------------------
// Weight fp32 -> bf16 conversion (4 matrices in one grid-stride kernel)
// ---------------------------------------------------------------------------
__global__ void wcvt_kernel(const float* __restrict__ w0, const float* __restrict__ w1,
                            const float* __restrict__ w2, const float* __restrict__ w3,
                            ushort_t* __restrict__ o0, ushort_t* __restrict__ o1,
                            ushort_t* __restrict__ o2, ushort_t* __restrict__ o3) {
  const int n1 = 2304 * 768, n3 = 768 * 768;
  const int total = 2 * n1 + 2 * n3;
  for (int i = blockIdx.x * blockDim.x + threadIdx.x; i < total; i += gridDim.x * blockDim.x) {
    if (i < n1) o0[i] = f2b(w0[i]);
    else if (i < 2 * n1) o1[i - n1] = f2b(w1[i - n1]);
    else if (i < 2 * n1 + n3) o2[i - 2 * n1] = f2b(w2[i - 2 * n1]);
    else o3[i - 2 * n1 - n3] = f2b(w3[i - 2 * n1 - n3]);
  }
}

// ---------------------------------------------------------------------------
// GroupNorm stats: blocks 0..127 video (b*32+g), 128..255 audio
// ---------------------------------------------------------------------------
__global__ void gn_stats_kernel(const float* __restrict__ video, const float* __restrict__ audio,
                                float* __restrict__ mu, float* __restrict__ rs) {
  const int bid = blockIdx.x;
  const bool isv = bid < 128;
  const int bg = bid & 127, b = bg >> 5, g = bg & 31;
  const int tid = threadIdx.x;
  float s = 0.f, ss = 0.f;
  if (isv) {
    for (int i = tid; i < 24 * 4096; i += 256) {
      int cl = i >> 12, tt = i & 4095;
      int f = tt >> 8, hw = tt & 255;
      float v = video[((size_t)((b * 16 + f) * 768 + g * 24 + cl)) * 256 + hw];
      s += v; ss += v * v;
    }
  } else {
    for (int i = tid; i < 24 * 1024; i += 256) {
      int cl = i >> 10, tt = i & 1023;
      float v = audio[((size_t)(b * 768 + g * 24 + cl)) * 1024 + tt];
      s += v; ss += v * v;
    }
  }
  for (int off = 32; off > 0; off >>= 1) { s += __shfl_down(s, off, 64); ss += __shfl_down(ss, off, 64); }
  __shared__ float red[8];
  int wv = tid >> 6, ln = tid & 63;
  if (ln == 0) { red[wv * 2] = s; red[wv * 2 + 1] = ss; }
  __syncthreads();
  if (tid == 0) {
    float S = red[0] + red[2] + red[4] + red[6];
    float SS = red[1] + red[3] + red[5] + red[7];
    float N = isv ? (24.f * 4096.f) : (24.f * 1024.f);
    float m = S / N;
    float var = SS / N - m * m;
    mu[bid] = m;
    rs[bid] = rsqrtf(var + 1e-5f);
  }
}

// ---------------------------------------------------------------------------
// Normalize video -> token-major bf16  Xv[n][c], n = b*4096 + f*256 + hw
// grid: 4*16*24 blocks (b,f,ctile32), 256 threads
// ---------------------------------------------------------------------------
__global__ void norm_video_kernel(const float* __restrict__ video,
                                  const float* __restrict__ mu, const float* __restrict__ rs,
                                  const float* __restrict__ sc, const float* __restrict__ bi,
                                  ushort_t* __restrict__ Xv) {
  __shared__ float T[32][257];
  const int bx = blockIdx.x;
  const int bf = bx / 24, ct = bx % 24;
  const int b = bf >> 4, f = bf & 15;
  const int c0 = ct * 32;
  const int tid = threadIdx.x;
  for (int i = 0; i < 32; ++i) {
    int c = c0 + i;
    int g = c / 24;
    float m = mu[b * 32 + g], r = rs[b * 32 + g];
    float v = video[((size_t)((b * 16 + f) * 768 + c)) * 256 + tid];
    T[i][tid] = (v - m) * r * sc[c] + bi[c];
  }
  __syncthreads();
  for (int i = 0; i < 32; ++i) {
    int id = i * 256 + tid;
    int c = id & 31, hw = id >> 5;
    Xv[((size_t)(b * 4096 + f * 256 + hw)) * 768 + c0 + c] = f2b(T[c][hw]);
  }
}

// Normalize audio -> token-major bf16  Xa[n][c], n = b*1024 + t
// grid: 16*24 blocks (b,ttile256,ctile32)
__global__ void norm_audio_kernel(const float* __restrict__ audio,
                                  const float* __restrict__ mu, const float* __restrict__ rs,
                                  const float* __restrict__ sc, const float* __restrict__ bi,
                                  ushort_t* __restrict__ Xa) {
  __shared__ float T[32][257];
  const int bx = blockIdx.x;
  const int bt = bx / 24, ct = bx % 24;
  const int b = bt >> 2, t0 = (bt & 3) * 256;
  const int c0 = ct * 32;
  const int tid = threadIdx.x;
  for (int i = 0; i < 32; ++i) {
    int c = c0 + i;
    int g = c / 24;
    float m = mu[128 + b * 32 + g], r = rs[128 + b * 32 + g];
    float v = audio[((size_t)(b * 768 + c)) * 1024 + t0 + tid];
    T[i][tid] = (v - m) * r * sc[c] + bi[c];
  }
  __syncthreads();
  for (int i = 0; i < 32; ++i) {
    int id = i * 256 + tid;
    int c = id & 31, tt = id >> 5;
    Xa[((size_t)(b * 1024 + t0 + tt)) * 768 + c0 + c] = f2b(T[c][tt]);
  }
}

// ---------------------------------------------------------------------------
// MFMA GEMM:  D[token m][o n] = sum_c A[m][c] * W[n][c]   (A,W bf16, row-major k-contig)
// 128x128 tile per 256-thread block; BK=64; K=768.
// MODE 0: QKV epilogue (+bias): n<768 -> Qt token-major; <1536 -> Kt; else Vc channel-major
// MODE 1: video proj: fp32 out ((b f) o hw) = residual + D + bias
// MODE 2: audio proj: fp32 out (b o t)      = residual + D + bias
// ---------------------------------------------------------------------------
template <int MODE>
__global__ __launch_bounds__(256) void gemm_kernel(
    const ushort_t* __restrict__ A, const ushort_t* __restrict__ W,
    const float* __restrict__ bias,
    void* __restrict__ p0, void* __restrict__ p1, void* __restrict__ p2,
    int M) {
  __shared__ ushort_t sm[18432];
  ushort_t* sA = sm;
  ushort_t* sB = sm + 9216;
  const int tid = threadIdx.x;
  const int lane = tid & 63, wave = tid >> 6;
  const int quad = lane >> 4, l16 = lane & 15;
  const int n0 = blockIdx.x * 128, m0 = blockIdx.y * 128;
  const int wm = (wave & 1) * 64, wn = (wave >> 1) * 64;

  f32x4 acc[4][4];
#pragma unroll
  for (int i = 0; i < 4; ++i)
#pragma unroll
    for (int j = 0; j < 4; ++j) acc[i][j] = (f32x4){0.f, 0.f, 0.f, 0.f};

  for (int kc = 0; kc < 768; kc += 64) {
#pragma unroll
    for (int i = 0; i < 4; ++i) {
      int cid = i * 256 + tid;
      int row = cid >> 3, ch = cid & 7;
      *reinterpret_cast<uint4*>(sA + row * 72 + ch * 8) =
          *reinterpret_cast<const uint4*>(A + (size_t)(m0 + row) * 768 + kc + ch * 8);
      *reinterpret_cast<uint4*>(sB + row * 72 + ch * 8) =
          *reinterpret_cast<const uint4*>(W + (size_t)(n0 + row) * 768 + kc + ch * 8);
    }
    __syncthreads();
#pragma unroll
    for (int ks = 0; ks < 2; ++ks) {
      short8 av[4], bv[4];
#pragma unroll
      for (int im = 0; im < 4; ++im)
        av[im] = *reinterpret_cast<const short8*>(sA + (wm + im * 16 + l16) * 72 + ks * 32 + quad * 8);
#pragma unroll
      for (int in = 0; in < 4; ++in)
        bv[in] = *reinterpret_cast<const short8*>(sB + (wn + in * 16 + l16) * 72 + ks * 32 + quad * 8);
#pragma unroll
      for (int im = 0; im < 4; ++im)
#pragma unroll
        for (int in = 0; in < 4; ++in)
          acc[im][in] = __builtin_amdgcn_mfma_f32_16x16x32_bf16(av[im], bv[in], acc[im][in], 0, 0, 0);
    }
    __syncthreads();
  }

  ushort_t* sC = sm;  // epilogue scratch [128][136] bf16
  if (MODE == 0) {
    const int section = n0 / 768;  // 0=Q 1=K 2=V
    const int obase = n0 - section * 768;
    if (section < 2) {
      // token-major store: sC[token][o]
#pragma unroll
      for (int in = 0; in < 4; ++in) {
        int ol = wn + in * 16 + l16;
        float bv_ = bias[n0 + ol];
#pragma unroll
        for (int im = 0; im < 4; ++im)
#pragma unroll
          for (int r = 0; r < 4; ++r) {
            int row = wm + im * 16 + quad * 4 + r;
            sC[row * 136 + ol] = f2b(acc[im][in][r] + bv_);
          }
      }
      __syncthreads();
      ushort_t* dst = (ushort_t*)(section == 0 ? p0 : p1);
#pragma unroll
      for (int i = 0; i < 8; ++i) {
        int cid = i * 256 + tid;
        int row = cid >> 4, ch = cid & 15;
        *reinterpret_cast<uint4*>(dst + (size_t)(m0 + row) * 768 + obase + ch * 8) =
            *reinterpret_cast<const uint4*>(sC + row * 136 + ch * 8);
      }
    } else {
      // channel-major store for V: sC[o][token]
#pragma unroll
      for (int in = 0; in < 4; ++in) {
        int ol = wn + in * 16 + l16;
        float bv_ = bias[n0 + ol];
#pragma unroll
        for (int im = 0; im < 4; ++im)
#pragma unroll
          for (int r = 0; r < 4; ++r) {
            int mr = wm + im * 16 + quad * 4 + r;
            sC[ol * 136 + mr] = f2b(acc[im][in][r] + bv_);
          }
      }
      __syncthreads();
      ushort_t* dst = (ushort_t*)p2;
#pragma unroll
      for (int i = 0; i < 8; ++i) {
        int cid = i * 256 + tid;
        int o = cid >> 4, ch = cid & 15;
        *reinterpret_cast<uint4*>(dst + (size_t)(obase + o) * M + m0 + ch * 8) =
            *reinterpret_cast<const uint4*>(sC + o * 136 + ch * 8);
      }
    }
  } else {
    // proj: channel-major + bias, then fp32 out = residual + val
#pragma unroll
    for (int in = 0; in < 4; ++in) {
      int ol = wn + in * 16 + l16;
      float bv_ = bias[n0 + ol];
#pragma unroll
      for (int im = 0; im < 4; ++im)
#pragma unroll
        for (int r = 0; r < 4; ++r) {
          int mr = wm + im * 16 + quad * 4 + r;
          sC[ol * 136 + mr] = f2b(acc[im][in][r] + bv_);
        }
    }
    __syncthreads();
    float* outp = (float*)p0;
    const float* resp = (const float*)p1;
#pragma unroll
    for (int i = 0; i < 16; ++i) {
      int cid = i * 256 + tid;
      int o = cid >> 5, ch = cid & 31;
      uint2 pk = *reinterpret_cast<const uint2*>(sC + o * 136 + ch * 4);
      size_t gidx;
      if (MODE == 1) {
        int b = m0 >> 12, f = (m0 >> 8) & 15, hw0 = m0 & 255;
        gidx = ((size_t)((b * 16 + f) * 768 + n0 + o)) * 256 + hw0 + ch * 4;
      } else {
        int b = m0 >> 10, t0 = m0 & 1023;
        gidx = ((size_t)(b * 768 + n0 + o)) * 1024 + t0 + ch * 4;
      }
      float4 rv = *reinterpret_cast<const float4*>(resp + gidx);
      float4 ov;
      ov.x = rv.x + b2f(pk.x & 0xffff);
      ov.y = rv.y + b2f(pk.x >> 16);
      ov.z = rv.z + b2f(pk.y & 0xffff);
      ov.w = rv.w + b2f(pk.y >> 16);
      *reinterpret_cast<float4*>(outp + gidx) = ov;
    }
  }
}

// ---------------------------------------------------------------------------
// Windowed cross-attention, flash-style over s-tiles of 256.
// SW: s tokens per window (256 att1 / 1024 att2); QW: q tokens per window.
// Block: (b, h, win, qchunk of 32 q). 256 threads. Per-wave-local softmax state.
// Qt/Kt token-major [tok][768]; Vc channel-major [768][Ms]; Ot token-major.
// ---------------------------------------------------------------------------
template <int SW, int QW>
__global__ __launch_bounds__(256) void attn_kernel(
    const ushort_t* __restrict__ Qt, const ushort_t* __restrict__ Kt,
    const ushort_t* __restrict__ Vc, ushort_t* __restrict__ Ot,
    int TQb, int TSb, int Ms) {
  __shared__ ushort_t KV[64 * 256];   // K then V tile, XOR-swizzled b64 chunks
  __shared__ float Qs[64 * 33];       // Q[c][q] fp32, pre-scaled by 0.125
  __shared__ ushort_t Ps[32 * 256];   // P bf16, swizzled
  __shared__ float mrow[32], lrow[32], arow[32];

  const int tid = threadIdx.x;
  const int NQC = QW / 32;
  const int bx = blockIdx.x;
  const int qc = bx % NQC;
  const int win = (bx / NQC) & 3;
  const int h = (bx / (NQC * 4)) % 12;
  const int b = bx / (NQC * 48);
  const int hc = h * 64;
  const int nq0 = b * TQb + win * QW + qc * 32;

  const int c_ = tid & 63;
  const int qb = tid >> 6;
  // stage Q (scale^2 = ch^-0.5 = 0.125 folded in)
#pragma unroll
  for (int j = 0; j < 8; ++j) {
    int q = qb * 8 + j;
    Qs[c_ * 33 + q] = 0.125f * b2f(Qt[(size_t)(nq0 + q) * 768 + hc + c_]);
  }
  if (tid < 32) { mrow[tid] = -1e30f; lrow[tid] = 0.f; }
  float ov[8];
#pragma unroll
  for (int j = 0; j < 8; ++j) ov[j] = 0.f;

  const int qt = tid >> 5;  // 0..7 -> q0 = qt*4 (rows wave-local: wave w owns q 8w..8w+7)
  const int st = tid & 31;
  const int q0 = qt * 4;
  const int s0 = st * 8;

  for (int tile = 0; tile < SW / 256; ++tile) {
    const int ns0 = b * TSb + win * SW + tile * 256;
    __syncthreads();  // Q/init visible; prior PV done before KV overwrite
    // ---- stage K: lane=c, 4 s per write, coalesced global reads across c
    for (int sg = qb; sg < 64; sg += 4) {
      int ss = sg * 4;
      unsigned long long k0 = Kt[(size_t)(ns0 + ss + 0) * 768 + hc + c_];
      unsigned long long k1 = Kt[(size_t)(ns0 + ss + 1) * 768 + hc + c_];
      unsigned long long k2 = Kt[(size_t)(ns0 + ss + 2) * 768 + hc + c_];
      unsigned long long k3 = Kt[(size_t)(ns0 + ss + 3) * 768 + hc + c_];
      int pc = (ss >> 2) ^ c_;
      *reinterpret_cast<unsigned long long*>(KV + c_ * 256 + pc * 4) =
          k0 | (k1 << 16) | (k2 << 32) | (k3 << 48);
    }
    __syncthreads();
    // ---- scores: 4q x 8s per thread
    float scq[4][8];
#pragma unroll
    for (int i = 0; i < 4; ++i)
#pragma unroll
      for (int j = 0; j < 8; ++j) scq[i][j] = 0.f;
    for (int cc = 0; cc < 64; ++cc) {
      float qv0 = Qs[cc * 33 + q0 + 0];
      float qv1 = Qs[cc * 33 + q0 + 1];
      float qv2 = Qs[cc * 33 + q0 + 2];
      float qv3 = Qs[cc * 33 + q0 + 3];
      int pc0 = (s0 >> 2) ^ cc;
      int pc1 = ((s0 >> 2) + 1) ^ cc;
      uint2 ka = *reinterpret_cast<const uint2*>(KV + cc * 256 + pc0 * 4);
      uint2 kb = *reinterpret_cast<const uint2*>(KV + cc * 256 + pc1 * 4);
      float kf[8];
      kf[0] = b2f(ka.x & 0xffff); kf[1] = b2f(ka.x >> 16);
      kf[2] = b2f(ka.y & 0xffff); kf[3] = b2f(ka.y >> 16);
      kf[4] = b2f(kb.x & 0xffff); kf[5] = b2f(kb.x >> 16);
      kf[6] = b2f(kb.y & 0xffff); kf[7] = b2f(kb.y >> 16);
#pragma unroll
      for (int j = 0; j < 8; ++j) {
        scq[0][j] += qv0 * kf[j];
        scq[1][j] += qv1 * kf[j];
        scq[2][j] += qv2 * kf[j];
        scq[3][j] += qv3 * kf[j];
      }
    }
    // ---- online softmax (rows wave-local; reduce across 32-lane groups)
#pragma unroll
    for (int i = 0; i < 4; ++i) {
      float m_ = scq[i][0];
#pragma unroll
      for (int j = 1; j < 8; ++j) m_ = fmaxf(m_, scq[i][j]);
#pragma unroll
      for (int off = 16; off > 0; off >>= 1) m_ = fmaxf(m_, __shfl_xor(m_, off, 32));
      float mold = mrow[q0 + i];
      float mnew = fmaxf(mold, m_);
      float a_ = __expf(mold - mnew);
      float l_ = 0.f;
#pragma unroll
      for (int j = 0; j < 8; ++j) {
        float p = __expf(scq[i][j] - mnew);
        scq[i][j] = p;
        l_ += p;
      }
#pragma unroll
      for (int off = 16; off > 0; off >>= 1) l_ += __shfl_xor(l_, off, 32);
      if (st == 0) {
        mrow[q0 + i] = mnew;
        lrow[q0 + i] = lrow[q0 + i] * a_ + l_;
        arow[q0 + i] = a_;
      }
      int q = q0 + i;
      int pp0 = (s0 >> 2) ^ q;
      int pp1 = ((s0 >> 2) + 1) ^ q;
      unsigned int w0 = (unsigned int)f2b(scq[i][0]) | ((unsigned int)f2b(scq[i][1]) << 16);
      unsigned int w1 = (unsigned int)f2b(scq[i][2]) | ((unsigned int)f2b(scq[i][3]) << 16);
      unsigned int w2 = (unsigned int)f2b(scq[i][4]) | ((unsigned int)f2b(scq[i][5]) << 16);
      unsigned int w3 = (unsigned int)f2b(scq[i][6]) | ((unsigned int)f2b(scq[i][7]) << 16);
      *reinterpret_cast<uint2*>(Ps + q * 256 + pp0 * 4) = make_uint2(w0, w1);
      *reinterpret_cast<uint2*>(Ps + q * 256 + pp1 * 4) = make_uint2(w2, w3);
    }
    __syncthreads();  // all waves done reading K
    // ---- stage V (channel-major source: lane=s coalesced)
    {
      int sl = tid & 63;
      int cb = tid >> 6;
      for (int ci = 0; ci < 16; ++ci) {
        int c = cb + ci * 4;
        const ushort_t* vrow = Vc + (size_t)(hc + c) * Ms + ns0;
#pragma unroll
        for (int sb = 0; sb < 4; ++sb) {
          int s = sb * 64 + sl;
          KV[c * 256 + (((s >> 2) ^ c) << 2) + (s & 3)] = vrow[s];
        }
      }
    }
    __syncthreads();
    // ---- rescale + PV: thread owns (c_, q = qb*8+j)
#pragma unroll
    for (int j = 0; j < 8; ++j) ov[j] *= arow[qb * 8 + j];
    for (int s4 = 0; s4 < 256; s4 += 4) {
      int pcv = (s4 >> 2) ^ c_;
      uint2 vv = *reinterpret_cast<const uint2*>(KV + c_ * 256 + pcv * 4);
      float vf0 = b2f(vv.x & 0xffff), vf1 = b2f(vv.x >> 16);
      float vf2 = b2f(vv.y & 0xffff), vf3 = b2f(vv.y >> 16);
#pragma unroll
      for (int j = 0; j < 8; ++j) {
        int q = qb * 8 + j;
        uint2 pp = *reinterpret_cast<const uint2*>(Ps + q * 256 + (((s4 >> 2) ^ q) << 2));
        ov[j] += b2f(pp.x & 0xffff) * vf0 + b2f(pp.x >> 16) * vf1 +
                 b2f(pp.y & 0xffff) * vf2 + b2f(pp.y >> 16) * vf3;
      }
    }
  }
  // ---- finalize
#pragma unroll
  for (int j = 0; j < 8; ++j) {
    int q = qb * 8 + j;
    float o = ov[j] * (1.f / lrow[q]);
    Ot[(size_t)(nq0 + q) * 768 + hc + c_] = f2b(o);
  }
}

// ---------------------------------------------------------------------------
extern "C" void kernel_launch(void* const* d_in, const int* in_sizes, int n_in,
                              void* d_out, int out_size, void* d_ws, size_t ws_size,
                              hipStream_t stream) {
  (void)in_sizes; (void)n_in; (void)out_size; (void)ws_size;
  const float* video = (const float*)d_in[0];
  const float* audio = (const float*)d_in[1];
  const float* vn_s = (const float*)d_in[2];
  const float* vn_b = (const float*)d_in[3];
  const float* an_s = (const float*)d_in[4];
  const float* an_b = (const float*)d_in[5];
  const float* vqkv_w = (const float*)d_in[6];
  const float* vqkv_b = (const float*)d_in[7];
  const float* aqkv_w = (const float*)d_in[8];
  const float* aqkv_b = (const float*)d_in[9];
  const float* vproj_w = (const float*)d_in[10];
  const float* vproj_b = (const float*)d_in[11];
  const float* aproj_w = (const float*)d_in[12];
  const float* aproj_b = (const float*)d_in[13];

  float* out_v = (float*)d_out;
  float* out_a = out_v + (size_t)4 * 16 * 768 * 16 * 16;

  char* ws = (char*)d_ws;
  size_t off = 0;
  auto carve = [&](size_t bytes) {
    char* p = ws + off;
    off += (bytes + 255) & ~(size_t)255;
    return p;
  };
  float* mu = (float*)carve(256 * 4);
  float* rs = (float*)carve(256 * 4);
  ushort_t* Xv = (ushort_t*)carve((size_t)16384 * 768 * 2);
  ushort_t* Xa = (ushort_t*)carve((size_t)4096 * 768 * 2);
  ushort_t* Wqv = (ushort_t*)carve((size_t)2304 * 768 * 2);
  ushort_t* Wqa = (ushort_t*)carve((size_t)2304 * 768 * 2);
  ushort_t* Wpv = (ushort_t*)carve((size_t)768 * 768 * 2);
  ushort_t* Wpa = (ushort_t*)carve((size_t)768 * 768 * 2);
  ushort_t* Qv = (ushort_t*)carve((size_t)16384 * 768 * 2);
  ushort_t* Kv = (ushort_t*)carve((size_t)16384 * 768 * 2);
  ushort_t* Vv = (ushort_t*)carve((size_t)16384 * 768 * 2);
  ushort_t* Qa = (ushort_t*)carve((size_t)4096 * 768 * 2);
  ushort_t* Ka = (ushort_t*)carve((size_t)4096 * 768 * 2);
  ushort_t* Va = (ushort_t*)carve((size_t)4096 * 768 * 2);
  ushort_t* Ov = Xv;  // alias: X no longer needed after QKV GEMM
  ushort_t* Oa = Xa;

  wcvt_kernel<<<1024, 256, 0, stream>>>(vqkv_w, aqkv_w, vproj_w, aproj_w, Wqv, Wqa, Wpv, Wpa);
  gn_stats_kernel<<<256, 256, 0, stream>>>(video, audio, mu, rs);
  norm_video_kernel<<<1536, 256, 0, stream>>>(video, mu, rs, vn_s, vn_b, Xv);
  norm_audio_kernel<<<384, 256, 0, stream>>>(audio, mu, rs, an_s, an_b, Xa);
  gemm_kernel<0><<<dim3(18, 128), 256, 0, stream>>>(Xv, Wqv, vqkv_b, Qv, Kv, Vv, 16384);
  gemm_kernel<0><<<dim3(18, 32), 256, 0, stream>>>(Xa, Wqa, aqkv_b, Qa, Ka, Va, 4096);
  // video queries attend audio windows
  attn_kernel<256, 1024><<<6144, 256, 0, stream>>>(Qv, Ka, Va, Ov, 4096, 1024, 4096);
  // audio queries attend video windows
  attn_kernel<1024, 256><<<1536, 256, 0, stream>>>(Qa, Kv, Vv, Oa, 1024, 4096, 16384);
  gemm_kernel<1><<<dim3(6, 128), 256, 0, stream>>>(Ov, Wpv, vproj_b, (void*)out_v, (void*)video, nullptr, 16384);
  gemm_kernel<2><<<dim3(6, 32), 256, 0, stream>>>(Oa, Wpa, aproj_b, (void*)out_a, (void*)audio, nullptr, 4096);
}

// Round 2
// 589.584 us; speedup vs baseline: 2.2598x; 2.2598x over previous
//
#include <hip/hip_runtime.h>
#include <hip/hip_bf16.h>

typedef unsigned short ushort_t;
typedef __attribute__((ext_vector_type(8))) short short8;
typedef __attribute__((ext_vector_type(4))) float f32x4;

#define DI __device__ __forceinline__

DI float b2f(unsigned int u16) {
  union { unsigned int i; float f; } v;
  v.i = u16 << 16;
  return v.f;
}
DI ushort_t f2b(float f) {
  union { float f; unsigned int u; } v; v.f = f;
  unsigned int r = v.u + 0x7FFFu + ((v.u >> 16) & 1u);
  return (ushort_t)(r >> 16);
}

// ---------------------------------------------------------------------------
// Weight fp32 -> bf16 conversion (4 matrices in one grid-stride kernel)
// ---------------------------------------------------------------------------
__global__ void wcvt_kernel(const float* __restrict__ w0, const float* __restrict__ w1,
                            const float* __restrict__ w2, const float* __restrict__ w3,
                            ushort_t* __restrict__ o0, ushort_t* __restrict__ o1,
                            ushort_t* __restrict__ o2, ushort_t* __restrict__ o3) {
  const int n1 = 2304 * 768, n3 = 768 * 768;
  const int total = 2 * n1 + 2 * n3;
  for (int i = blockIdx.x * blockDim.x + threadIdx.x; i < total; i += gridDim.x * blockDim.x) {
    if (i < n1) o0[i] = f2b(w0[i]);
    else if (i < 2 * n1) o1[i - n1] = f2b(w1[i - n1]);
    else if (i < 2 * n1 + n3) o2[i - 2 * n1] = f2b(w2[i - 2 * n1]);
    else o3[i - 2 * n1 - n3] = f2b(w3[i - 2 * n1 - n3]);
  }
}

// ---------------------------------------------------------------------------
// GroupNorm stats: blocks 0..127 video (b*32+g), 128..255 audio
// ---------------------------------------------------------------------------
__global__ void gn_stats_kernel(const float* __restrict__ video, const float* __restrict__ audio,
                                float* __restrict__ mu, float* __restrict__ rs) {
  const int bid = blockIdx.x;
  const bool isv = bid < 128;
  const int bg = bid & 127, b = bg >> 5, g = bg & 31;
  const int tid = threadIdx.x;
  float s = 0.f, ss = 0.f;
  if (isv) {
    for (int i = tid; i < 24 * 4096; i += 256) {
      int cl = i >> 12, tt = i & 4095;
      int f = tt >> 8, hw = tt & 255;
      float v = video[((size_t)((b * 16 + f) * 768 + g * 24 + cl)) * 256 + hw];
      s += v; ss += v * v;
    }
  } else {
    for (int i = tid; i < 24 * 1024; i += 256) {
      int cl = i >> 10, tt = i & 1023;
      float v = audio[((size_t)(b * 768 + g * 24 + cl)) * 1024 + tt];
      s += v; ss += v * v;
    }
  }
  for (int off = 32; off > 0; off >>= 1) { s += __shfl_down(s, off, 64); ss += __shfl_down(ss, off, 64); }
  __shared__ float red[8];
  int wv = tid >> 6, ln = tid & 63;
  if (ln == 0) { red[wv * 2] = s; red[wv * 2 + 1] = ss; }
  __syncthreads();
  if (tid == 0) {
    float S = red[0] + red[2] + red[4] + red[6];
    float SS = red[1] + red[3] + red[5] + red[7];
    float N = isv ? (24.f * 4096.f) : (24.f * 1024.f);
    float m = S / N;
    float var = SS / N - m * m;
    mu[bid] = m;
    rs[bid] = rsqrtf(var + 1e-5f);
  }
}

// ---------------------------------------------------------------------------
// Normalize video -> token-major bf16  Xv[n][c], n = b*4096 + f*256 + hw
// ---------------------------------------------------------------------------
__global__ void norm_video_kernel(const float* __restrict__ video,
                                  const float* __restrict__ mu, const float* __restrict__ rs,
                                  const float* __restrict__ sc, const float* __restrict__ bi,
                                  ushort_t* __restrict__ Xv) {
  __shared__ float T[32][257];
  const int bx = blockIdx.x;
  const int bf = bx / 24, ct = bx % 24;
  const int b = bf >> 4, f = bf & 15;
  const int c0 = ct * 32;
  const int tid = threadIdx.x;
  for (int i = 0; i < 32; ++i) {
    int c = c0 + i;
    int g = c / 24;
    float m = mu[b * 32 + g], r = rs[b * 32 + g];
    float v = video[((size_t)((b * 16 + f) * 768 + c)) * 256 + tid];
    T[i][tid] = (v - m) * r * sc[c] + bi[c];
  }
  __syncthreads();
  for (int i = 0; i < 32; ++i) {
    int id = i * 256 + tid;
    int c = id & 31, hw = id >> 5;
    Xv[((size_t)(b * 4096 + f * 256 + hw)) * 768 + c0 + c] = f2b(T[c][hw]);
  }
}

// Normalize audio -> token-major bf16  Xa[n][c], n = b*1024 + t
__global__ void norm_audio_kernel(const float* __restrict__ audio,
                                  const float* __restrict__ mu, const float* __restrict__ rs,
                                  const float* __restrict__ sc, const float* __restrict__ bi,
                                  ushort_t* __restrict__ Xa) {
  __shared__ float T[32][257];
  const int bx = blockIdx.x;
  const int bt = bx / 24, ct = bx % 24;
  const int b = bt >> 2, t0 = (bt & 3) * 256;
  const int c0 = ct * 32;
  const int tid = threadIdx.x;
  for (int i = 0; i < 32; ++i) {
    int c = c0 + i;
    int g = c / 24;
    float m = mu[128 + b * 32 + g], r = rs[128 + b * 32 + g];
    float v = audio[((size_t)(b * 768 + c)) * 1024 + t0 + tid];
    T[i][tid] = (v - m) * r * sc[c] + bi[c];
  }
  __syncthreads();
  for (int i = 0; i < 32; ++i) {
    int id = i * 256 + tid;
    int c = id & 31, tt = id >> 5;
    Xa[((size_t)(b * 1024 + t0 + tt)) * 768 + c0 + c] = f2b(T[c][tt]);
  }
}

// ---------------------------------------------------------------------------
// MFMA GEMM:  D[token m][o n] = sum_c A[m][c] * W[n][c]
// MODE 0: QKV epilogue; MODE 1: video proj; MODE 2: audio proj (residual add)
// ---------------------------------------------------------------------------
template <int MODE>
__global__ __launch_bounds__(256) void gemm_kernel(
    const ushort_t* __restrict__ A, const ushort_t* __restrict__ W,
    const float* __restrict__ bias,
    void* __restrict__ p0, void* __restrict__ p1, void* __restrict__ p2,
    int M) {
  __shared__ ushort_t sm[18432];
  ushort_t* sA = sm;
  ushort_t* sB = sm + 9216;
  const int tid = threadIdx.x;
  const int lane = tid & 63, wave = tid >> 6;
  const int quad = lane >> 4, l16 = lane & 15;
  const int n0 = blockIdx.x * 128, m0 = blockIdx.y * 128;
  const int wm = (wave & 1) * 64, wn = (wave >> 1) * 64;

  f32x4 acc[4][4];
#pragma unroll
  for (int i = 0; i < 4; ++i)
#pragma unroll
    for (int j = 0; j < 4; ++j) acc[i][j] = (f32x4){0.f, 0.f, 0.f, 0.f};

  for (int kc = 0; kc < 768; kc += 64) {
#pragma unroll
    for (int i = 0; i < 4; ++i) {
      int cid = i * 256 + tid;
      int row = cid >> 3, ch = cid & 7;
      *reinterpret_cast<uint4*>(sA + row * 72 + ch * 8) =
          *reinterpret_cast<const uint4*>(A + (size_t)(m0 + row) * 768 + kc + ch * 8);
      *reinterpret_cast<uint4*>(sB + row * 72 + ch * 8) =
          *reinterpret_cast<const uint4*>(W + (size_t)(n0 + row) * 768 + kc + ch * 8);
    }
    __syncthreads();
#pragma unroll
    for (int ks = 0; ks < 2; ++ks) {
      short8 av[4], bv[4];
#pragma unroll
      for (int im = 0; im < 4; ++im)
        av[im] = *reinterpret_cast<const short8*>(sA + (wm + im * 16 + l16) * 72 + ks * 32 + quad * 8);
#pragma unroll
      for (int in = 0; in < 4; ++in)
        bv[in] = *reinterpret_cast<const short8*>(sB + (wn + in * 16 + l16) * 72 + ks * 32 + quad * 8);
#pragma unroll
      for (int im = 0; im < 4; ++im)
#pragma unroll
        for (int in = 0; in < 4; ++in)
          acc[im][in] = __builtin_amdgcn_mfma_f32_16x16x32_bf16(av[im], bv[in], acc[im][in], 0, 0, 0);
    }
    __syncthreads();
  }

  ushort_t* sC = sm;  // epilogue scratch [128][136] bf16
  if (MODE == 0) {
    const int section = n0 / 768;  // 0=Q 1=K 2=V
    const int obase = n0 - section * 768;
    if (section < 2) {
#pragma unroll
      for (int in = 0; in < 4; ++in) {
        int ol = wn + in * 16 + l16;
        float bv_ = bias[n0 + ol];
#pragma unroll
        for (int im = 0; im < 4; ++im)
#pragma unroll
          for (int r = 0; r < 4; ++r) {
            int row = wm + im * 16 + quad * 4 + r;
            sC[row * 136 + ol] = f2b(acc[im][in][r] + bv_);
          }
      }
      __syncthreads();
      ushort_t* dst = (ushort_t*)(section == 0 ? p0 : p1);
#pragma unroll
      for (int i = 0; i < 8; ++i) {
        int cid = i * 256 + tid;
        int row = cid >> 4, ch = cid & 15;
        *reinterpret_cast<uint4*>(dst + (size_t)(m0 + row) * 768 + obase + ch * 8) =
            *reinterpret_cast<const uint4*>(sC + row * 136 + ch * 8);
      }
    } else {
#pragma unroll
      for (int in = 0; in < 4; ++in) {
        int ol = wn + in * 16 + l16;
        float bv_ = bias[n0 + ol];
#pragma unroll
        for (int im = 0; im < 4; ++im)
#pragma unroll
          for (int r = 0; r < 4; ++r) {
            int mr = wm + im * 16 + quad * 4 + r;
            sC[ol * 136 + mr] = f2b(acc[im][in][r] + bv_);
          }
      }
      __syncthreads();
      ushort_t* dst = (ushort_t*)p2;
#pragma unroll
      for (int i = 0; i < 8; ++i) {
        int cid = i * 256 + tid;
        int o = cid >> 4, ch = cid & 15;
        *reinterpret_cast<uint4*>(dst + (size_t)(obase + o) * M + m0 + ch * 8) =
            *reinterpret_cast<const uint4*>(sC + o * 136 + ch * 8);
      }
    }
  } else {
#pragma unroll
    for (int in = 0; in < 4; ++in) {
      int ol = wn + in * 16 + l16;
      float bv_ = bias[n0 + ol];
#pragma unroll
      for (int im = 0; im < 4; ++im)
#pragma unroll
        for (int r = 0; r < 4; ++r) {
          int mr = wm + im * 16 + quad * 4 + r;
          sC[ol * 136 + mr] = f2b(acc[im][in][r] + bv_);
        }
    }
    __syncthreads();
    float* outp = (float*)p0;
    const float* resp = (const float*)p1;
#pragma unroll
    for (int i = 0; i < 16; ++i) {
      int cid = i * 256 + tid;
      int o = cid >> 5, ch = cid & 31;
      uint2 pk = *reinterpret_cast<const uint2*>(sC + o * 136 + ch * 4);
      size_t gidx;
      if (MODE == 1) {
        int b = m0 >> 12, f = (m0 >> 8) & 15, hw0 = m0 & 255;
        gidx = ((size_t)((b * 16 + f) * 768 + n0 + o)) * 256 + hw0 + ch * 4;
      } else {
        int b = m0 >> 10, t0 = m0 & 1023;
        gidx = ((size_t)(b * 768 + n0 + o)) * 1024 + t0 + ch * 4;
      }
      float4 rv = *reinterpret_cast<const float4*>(resp + gidx);
      float4 ov;
      ov.x = rv.x + b2f(pk.x & 0xffff);
      ov.y = rv.y + b2f(pk.x >> 16);
      ov.z = rv.z + b2f(pk.y & 0xffff);
      ov.w = rv.w + b2f(pk.y >> 16);
      *reinterpret_cast<float4*>(outp + gidx) = ov;
    }
  }
}

// ---------------------------------------------------------------------------
// MFMA flash attention over contiguous windows (shift=0).
// QW q-tokens / SW s-tokens per window, ch=64, NH=12.
// Block: 256 threads (4 waves), 64-q tile (wave w owns q rows w*16..w*16+15),
// s-tiles of 128. Q A-frags in registers; K staged [128 s][72] LDS; V staged
// [64 ch][136] LDS (same buffer); P round-trips via [64 q][136] LDS (the
// verified MFMA C-layout -> A-layout transform). Softmax state in registers
// (rows are wave-local; shfl_xor 1/2/4/8 reduces across the 16-lane col group).
// ---------------------------------------------------------------------------
template <int QW, int SW>
__global__ __launch_bounds__(256) void attn_mfma_kernel(
    const ushort_t* __restrict__ Qt, const ushort_t* __restrict__ Kt,
    const ushort_t* __restrict__ Vc, ushort_t* __restrict__ Ot,
    int TQb, int TSb, int Ms) {
  __shared__ ushort_t sK[128 * 72];   // K (stride 72) / V (stride 136) / Q staging
  __shared__ ushort_t sP[64 * 136];   // P bf16 / O bounce
  const int tid = threadIdx.x;
  const int lane = tid & 63, wave = tid >> 6;
  const int quad = lane >> 4, l16 = lane & 15;
  const int NQT = QW / 64;
  const int bx = blockIdx.x;
  const int qt = bx % NQT;
  const int win = (bx / NQT) & 3;
  const int h = (bx / (NQT * 4)) % 12;
  const int b = bx / (NQT * 48);
  const int hc = h * 64;
  const int nq0 = b * TQb + win * QW + qt * 64;
  const int ns_base = b * TSb + win * SW;

  // ---- stage Q (64 x 64) into sK (stride 72), scaled by 0.125 (= ch^-0.5,
  // exact in bf16: exponent shift only)
#pragma unroll
  for (int i = 0; i < 2; ++i) {
    int c = i * 256 + tid;
    int row = c >> 3, cc = c & 7;
    uint4 raw = *reinterpret_cast<const uint4*>(Qt + (size_t)(nq0 + row) * 768 + hc + cc * 8);
    unsigned int* rp = reinterpret_cast<unsigned int*>(&raw);
    uint4 out;
    unsigned int* op = reinterpret_cast<unsigned int*>(&out);
#pragma unroll
    for (int j = 0; j < 4; ++j) {
      unsigned int lo = (unsigned int)f2b(0.125f * b2f(rp[j] & 0xffff));
      unsigned int hi = (unsigned int)f2b(0.125f * b2f(rp[j] >> 16));
      op[j] = lo | (hi << 16);
    }
    *reinterpret_cast<uint4*>(sK + row * 72 + cc * 8) = out;
  }
  __syncthreads();
  short8 qf[2];
#pragma unroll
  for (int ks = 0; ks < 2; ++ks)
    qf[ks] = *reinterpret_cast<const short8*>(sK + (wave * 16 + l16) * 72 + ks * 32 + quad * 8);

  float mr[4], lr[4];
  f32x4 on[4];
#pragma unroll
  for (int r = 0; r < 4; ++r) { mr[r] = -1e30f; lr[r] = 0.f; }
#pragma unroll
  for (int nc = 0; nc < 4; ++nc) on[nc] = (f32x4){0.f, 0.f, 0.f, 0.f};

  for (int t = 0; t < SW / 128; ++t) {
    const int ns0 = ns_base + t * 128;
    __syncthreads();  // sK free (Q frags read / previous PV done)
    // ---- stage K tile [128 s][64 ch] token-major -> sK stride 72
#pragma unroll
    for (int i = 0; i < 4; ++i) {
      int c = i * 256 + tid;
      int row = c >> 3, cc = c & 7;
      *reinterpret_cast<uint4*>(sK + row * 72 + cc * 8) =
          *reinterpret_cast<const uint4*>(Kt + (size_t)(ns0 + row) * 768 + hc + cc * 8);
    }
    __syncthreads();
    // ---- S = Q K^T : 8 n-tiles x 2 k-steps
    f32x4 sf[8];
#pragma unroll
    for (int nt = 0; nt < 8; ++nt) sf[nt] = (f32x4){0.f, 0.f, 0.f, 0.f};
#pragma unroll
    for (int ks = 0; ks < 2; ++ks) {
#pragma unroll
      for (int nt = 0; nt < 8; ++nt) {
        short8 kf = *reinterpret_cast<const short8*>(sK + (nt * 16 + l16) * 72 + ks * 32 + quad * 8);
        sf[nt] = __builtin_amdgcn_mfma_f32_16x16x32_bf16(qf[ks], kf, sf[nt], 0, 0, 0);
      }
    }
    // ---- online softmax (row = quad*4+r, cols spread over l16 x nt)
#pragma unroll
    for (int r = 0; r < 4; ++r) {
      float m_ = sf[0][r];
#pragma unroll
      for (int nt = 1; nt < 8; ++nt) m_ = fmaxf(m_, sf[nt][r]);
#pragma unroll
      for (int off = 1; off < 16; off <<= 1) m_ = fmaxf(m_, __shfl_xor(m_, off));
      float mnew = fmaxf(mr[r], m_);
      float al = __expf(mr[r] - mnew);
      float ls = 0.f;
      int prow = (wave * 16 + quad * 4 + r) * 136;
#pragma unroll
      for (int nt = 0; nt < 8; ++nt) {
        float p = __expf(sf[nt][r] - mnew);
        ls += p;
        sP[prow + nt * 16 + l16] = f2b(p);
      }
#pragma unroll
      for (int off = 1; off < 16; off <<= 1) ls += __shfl_xor(ls, off);
      lr[r] = lr[r] * al + ls;
      mr[r] = mnew;
#pragma unroll
      for (int nc = 0; nc < 4; ++nc) on[nc][r] *= al;
    }
    __syncthreads();  // all waves done reading K
    // ---- stage V tile [64 ch][128 s] channel-major -> sK stride 136
#pragma unroll
    for (int i = 0; i < 4; ++i) {
      int c = i * 256 + tid;
      int ch = c >> 4, cc = c & 15;
      *reinterpret_cast<uint4*>(sK + ch * 136 + cc * 8) =
          *reinterpret_cast<const uint4*>(Vc + (size_t)(hc + ch) * Ms + ns0 + cc * 8);
    }
    __syncthreads();
    // ---- O += P V : 4 k-steps (s) x 4 n-tiles (ch)
#pragma unroll
    for (int ks = 0; ks < 4; ++ks) {
      short8 pf = *reinterpret_cast<const short8*>(sP + (wave * 16 + l16) * 136 + ks * 32 + quad * 8);
#pragma unroll
      for (int nc = 0; nc < 4; ++nc) {
        short8 vf = *reinterpret_cast<const short8*>(sK + (nc * 16 + l16) * 136 + ks * 32 + quad * 8);
        on[nc] = __builtin_amdgcn_mfma_f32_16x16x32_bf16(pf, vf, on[nc], 0, 0, 0);
      }
    }
  }
  // ---- finalize: O /= l, bounce through sP for coalesced writes
#pragma unroll
  for (int r = 0; r < 4; ++r) {
    float inv = 1.f / lr[r];
    int prow = (wave * 16 + quad * 4 + r) * 136;
#pragma unroll
    for (int nc = 0; nc < 4; ++nc)
      sP[prow + nc * 16 + l16] = f2b(on[nc][r] * inv);
  }
  __syncthreads();
#pragma unroll
  for (int i = 0; i < 2; ++i) {
    int c = i * 256 + tid;
    int row = c >> 3, cc = c & 7;
    *reinterpret_cast<uint4*>(Ot + (size_t)(nq0 + row) * 768 + hc + cc * 8) =
        *reinterpret_cast<const uint4*>(sP + row * 136 + cc * 8);
  }
}

// ---------------------------------------------------------------------------
extern "C" void kernel_launch(void* const* d_in, const int* in_sizes, int n_in,
                              void* d_out, int out_size, void* d_ws, size_t ws_size,
                              hipStream_t stream) {
  (void)in_sizes; (void)n_in; (void)out_size; (void)ws_size;
  const float* video = (const float*)d_in[0];
  const float* audio = (const float*)d_in[1];
  const float* vn_s = (const float*)d_in[2];
  const float* vn_b = (const float*)d_in[3];
  const float* an_s = (const float*)d_in[4];
  const float* an_b = (const float*)d_in[5];
  const float* vqkv_w = (const float*)d_in[6];
  const float* vqkv_b = (const float*)d_in[7];
  const float* aqkv_w = (const float*)d_in[8];
  const float* aqkv_b = (const float*)d_in[9];
  const float* vproj_w = (const float*)d_in[10];
  const float* vproj_b = (const float*)d_in[11];
  const float* aproj_w = (const float*)d_in[12];
  const float* aproj_b = (const float*)d_in[13];

  float* out_v = (float*)d_out;
  float* out_a = out_v + (size_t)4 * 16 * 768 * 16 * 16;

  char* ws = (char*)d_ws;
  size_t off = 0;
  auto carve = [&](size_t bytes) {
    char* p = ws + off;
    off += (bytes + 255) & ~(size_t)255;
    return p;
  };
  float* mu = (float*)carve(256 * 4);
  float* rs = (float*)carve(256 * 4);
  ushort_t* Xv = (ushort_t*)carve((size_t)16384 * 768 * 2);
  ushort_t* Xa = (ushort_t*)carve((size_t)4096 * 768 * 2);
  ushort_t* Wqv = (ushort_t*)carve((size_t)2304 * 768 * 2);
  ushort_t* Wqa = (ushort_t*)carve((size_t)2304 * 768 * 2);
  ushort_t* Wpv = (ushort_t*)carve((size_t)768 * 768 * 2);
  ushort_t* Wpa = (ushort_t*)carve((size_t)768 * 768 * 2);
  ushort_t* Qv = (ushort_t*)carve((size_t)16384 * 768 * 2);
  ushort_t* Kv = (ushort_t*)carve((size_t)16384 * 768 * 2);
  ushort_t* Vv = (ushort_t*)carve((size_t)16384 * 768 * 2);
  ushort_t* Qa = (ushort_t*)carve((size_t)4096 * 768 * 2);
  ushort_t* Ka = (ushort_t*)carve((size_t)4096 * 768 * 2);
  ushort_t* Va = (ushort_t*)carve((size_t)4096 * 768 * 2);
  ushort_t* Ov = Xv;  // alias: X no longer needed after QKV GEMM
  ushort_t* Oa = Xa;

  wcvt_kernel<<<1024, 256, 0, stream>>>(vqkv_w, aqkv_w, vproj_w, aproj_w, Wqv, Wqa, Wpv, Wpa);
  gn_stats_kernel<<<256, 256, 0, stream>>>(video, audio, mu, rs);
  norm_video_kernel<<<1536, 256, 0, stream>>>(video, mu, rs, vn_s, vn_b, Xv);
  norm_audio_kernel<<<384, 256, 0, stream>>>(audio, mu, rs, an_s, an_b, Xa);
  gemm_kernel<0><<<dim3(18, 128), 256, 0, stream>>>(Xv, Wqv, vqkv_b, Qv, Kv, Vv, 16384);
  gemm_kernel<0><<<dim3(18, 32), 256, 0, stream>>>(Xa, Wqa, aqkv_b, Qa, Ka, Va, 4096);
  // video queries attend audio windows: QW=1024, SW=256
  attn_mfma_kernel<1024, 256><<<3072, 256, 0, stream>>>(Qv, Ka, Va, Ov, 4096, 1024, 4096);
  // audio queries attend video windows: QW=256, SW=1024
  attn_mfma_kernel<256, 1024><<<768, 256, 0, stream>>>(Qa, Kv, Vv, Oa, 1024, 4096, 16384);
  gemm_kernel<1><<<dim3(6, 128), 256, 0, stream>>>(Ov, Wpv, vproj_b, (void*)out_v, (void*)video, nullptr, 16384);
  gemm_kernel<2><<<dim3(6, 32), 256, 0, stream>>>(Oa, Wpa, aproj_b, (void*)out_a, (void*)audio, nullptr, 4096);
}

// Round 3
// 446.302 us; speedup vs baseline: 2.9853x; 1.3210x over previous
//
#include <hip/hip_runtime.h>
#include <hip/hip_bf16.h>

typedef unsigned short ushort_t;
typedef __attribute__((ext_vector_type(8))) short short8;
typedef __attribute__((ext_vector_type(4))) float f32x4;

#define DI __device__ __forceinline__

DI float b2f(unsigned int u16) {
  union { unsigned int i; float f; } v;
  v.i = u16 << 16;
  return v.f;
}
DI ushort_t f2b(float f) {
  union { float f; unsigned int u; } v; v.f = f;
  unsigned int r = v.u + 0x7FFFu + ((v.u >> 16) & 1u);
  return (ushort_t)(r >> 16);
}

// ---------------------------------------------------------------------------
// Weight fp32 -> bf16 conversion (4 matrices in one grid-stride kernel)
// ---------------------------------------------------------------------------
__global__ void wcvt_kernel(const float* __restrict__ w0, const float* __restrict__ w1,
                            const float* __restrict__ w2, const float* __restrict__ w3,
                            ushort_t* __restrict__ o0, ushort_t* __restrict__ o1,
                            ushort_t* __restrict__ o2, ushort_t* __restrict__ o3) {
  const int n1 = 2304 * 768, n3 = 768 * 768;
  const int total = 2 * n1 + 2 * n3;
  for (int i = blockIdx.x * blockDim.x + threadIdx.x; i < total; i += gridDim.x * blockDim.x) {
    if (i < n1) o0[i] = f2b(w0[i]);
    else if (i < 2 * n1) o1[i - n1] = f2b(w1[i - n1]);
    else if (i < 2 * n1 + n3) o2[i - 2 * n1] = f2b(w2[i - 2 * n1]);
    else o3[i - 2 * n1 - n3] = f2b(w3[i - 2 * n1 - n3]);
  }
}

// ---------------------------------------------------------------------------
// GroupNorm stats, two-phase.
// Phase 1: blocks 0..2047 video (bg*16 + frame), 2048..2559 audio (bg*4 + part)
//          each reduces a coalesced 24x256-float slab -> (sum, sumsq) partial.
// Phase 2: one block; thread t < 128 folds 16 video partials, t >= 128 folds
//          4 audio partials -> mu[t], rs[t].
// ---------------------------------------------------------------------------
__global__ void gn_partial_kernel(const float* __restrict__ video,
                                  const float* __restrict__ audio,
                                  float* __restrict__ part) {
  const int bid = blockIdx.x;
  const int tid = threadIdx.x;
  float s = 0.f, ss = 0.f;
  if (bid < 2048) {
    int bg = bid >> 4, f = bid & 15;
    int b = bg >> 5, g = bg & 31;
    const float* base = video + ((size_t)((b * 16 + f) * 768 + g * 24)) * 256 + tid;
#pragma unroll
    for (int cl = 0; cl < 24; ++cl) {
      float v = base[cl * 256];
      s += v; ss += v * v;
    }
  } else {
    int a = bid - 2048;
    int bg = a >> 2, p = a & 3;
    int b = bg >> 5, g = bg & 31;
    const float* base = audio + ((size_t)(b * 768 + g * 24)) * 1024 + p * 256 + tid;
#pragma unroll
    for (int cl = 0; cl < 24; ++cl) {
      float v = base[cl * 1024];
      s += v; ss += v * v;
    }
  }
  for (int off = 32; off > 0; off >>= 1) { s += __shfl_down(s, off, 64); ss += __shfl_down(ss, off, 64); }
  __shared__ float red[8];
  int wv = tid >> 6, ln = tid & 63;
  if (ln == 0) { red[wv * 2] = s; red[wv * 2 + 1] = ss; }
  __syncthreads();
  if (tid == 0) {
    part[bid * 2] = red[0] + red[2] + red[4] + red[6];
    part[bid * 2 + 1] = red[1] + red[3] + red[5] + red[7];
  }
}

__global__ void gn_final_kernel(const float* __restrict__ part,
                                float* __restrict__ mu, float* __restrict__ rs) {
  const int tid = threadIdx.x;  // 0..255
  float s = 0.f, ss = 0.f;
  if (tid < 128) {
#pragma unroll
    for (int i = 0; i < 16; ++i) { s += part[(tid * 16 + i) * 2]; ss += part[(tid * 16 + i) * 2 + 1]; }
    const float N = 24.f * 4096.f;
    float m = s / N;
    mu[tid] = m;
    rs[tid] = rsqrtf(ss / N - m * m + 1e-5f);
  } else {
    int a = tid - 128;
#pragma unroll
    for (int i = 0; i < 4; ++i) { s += part[(2048 + a * 4 + i) * 2]; ss += part[(2048 + a * 4 + i) * 2 + 1]; }
    const float N = 24.f * 1024.f;
    float m = s / N;
    mu[tid] = m;
    rs[tid] = rsqrtf(ss / N - m * m + 1e-5f);
  }
}

// ---------------------------------------------------------------------------
// Normalize video -> token-major bf16  Xv[n][c], n = b*4096 + f*256 + hw
// ---------------------------------------------------------------------------
__global__ void norm_video_kernel(const float* __restrict__ video,
                                  const float* __restrict__ mu, const float* __restrict__ rs,
                                  const float* __restrict__ sc, const float* __restrict__ bi,
                                  ushort_t* __restrict__ Xv) {
  __shared__ float T[32][257];
  const int bx = blockIdx.x;
  const int bf = bx / 24, ct = bx % 24;
  const int b = bf >> 4, f = bf & 15;
  const int c0 = ct * 32;
  const int tid = threadIdx.x;
  for (int i = 0; i < 32; ++i) {
    int c = c0 + i;
    int g = c / 24;
    float m = mu[b * 32 + g], r = rs[b * 32 + g];
    float v = video[((size_t)((b * 16 + f) * 768 + c)) * 256 + tid];
    T[i][tid] = (v - m) * r * sc[c] + bi[c];
  }
  __syncthreads();
  for (int i = 0; i < 32; ++i) {
    int id = i * 256 + tid;
    int c = id & 31, hw = id >> 5;
    Xv[((size_t)(b * 4096 + f * 256 + hw)) * 768 + c0 + c] = f2b(T[c][hw]);
  }
}

// Normalize audio -> token-major bf16  Xa[n][c], n = b*1024 + t
__global__ void norm_audio_kernel(const float* __restrict__ audio,
                                  const float* __restrict__ mu, const float* __restrict__ rs,
                                  const float* __restrict__ sc, const float* __restrict__ bi,
                                  ushort_t* __restrict__ Xa) {
  __shared__ float T[32][257];
  const int bx = blockIdx.x;
  const int bt = bx / 24, ct = bx % 24;
  const int b = bt >> 2, t0 = (bt & 3) * 256;
  const int c0 = ct * 32;
  const int tid = threadIdx.x;
  for (int i = 0; i < 32; ++i) {
    int c = c0 + i;
    int g = c / 24;
    float m = mu[128 + b * 32 + g], r = rs[128 + b * 32 + g];
    float v = audio[((size_t)(b * 768 + c)) * 1024 + t0 + tid];
    T[i][tid] = (v - m) * r * sc[c] + bi[c];
  }
  __syncthreads();
  for (int i = 0; i < 32; ++i) {
    int id = i * 256 + tid;
    int c = id & 31, tt = id >> 5;
    Xa[((size_t)(b * 1024 + t0 + tt)) * 768 + c0 + c] = f2b(T[c][tt]);
  }
}

// ---------------------------------------------------------------------------
// MFMA GEMM:  D[token m][o n] = sum_c A[m][c] * W[n][c]
// MODE 0: QKV epilogue; MODE 1: video proj; MODE 2: audio proj (residual add)
// ---------------------------------------------------------------------------
template <int MODE>
__global__ __launch_bounds__(256) void gemm_kernel(
    const ushort_t* __restrict__ A, const ushort_t* __restrict__ W,
    const float* __restrict__ bias,
    void* __restrict__ p0, void* __restrict__ p1, void* __restrict__ p2,
    int M) {
  __shared__ ushort_t sm[18432];
  ushort_t* sA = sm;
  ushort_t* sB = sm + 9216;
  const int tid = threadIdx.x;
  const int lane = tid & 63, wave = tid >> 6;
  const int quad = lane >> 4, l16 = lane & 15;
  const int n0 = blockIdx.x * 128, m0 = blockIdx.y * 128;
  const int wm = (wave & 1) * 64, wn = (wave >> 1) * 64;

  f32x4 acc[4][4];
#pragma unroll
  for (int i = 0; i < 4; ++i)
#pragma unroll
    for (int j = 0; j < 4; ++j) acc[i][j] = (f32x4){0.f, 0.f, 0.f, 0.f};

  for (int kc = 0; kc < 768; kc += 64) {
#pragma unroll
    for (int i = 0; i < 4; ++i) {
      int cid = i * 256 + tid;
      int row = cid >> 3, ch = cid & 7;
      *reinterpret_cast<uint4*>(sA + row * 72 + ch * 8) =
          *reinterpret_cast<const uint4*>(A + (size_t)(m0 + row) * 768 + kc + ch * 8);
      *reinterpret_cast<uint4*>(sB + row * 72 + ch * 8) =
          *reinterpret_cast<const uint4*>(W + (size_t)(n0 + row) * 768 + kc + ch * 8);
    }
    __syncthreads();
#pragma unroll
    for (int ks = 0; ks < 2; ++ks) {
      short8 av[4], bv[4];
#pragma unroll
      for (int im = 0; im < 4; ++im)
        av[im] = *reinterpret_cast<const short8*>(sA + (wm + im * 16 + l16) * 72 + ks * 32 + quad * 8);
#pragma unroll
      for (int in = 0; in < 4; ++in)
        bv[in] = *reinterpret_cast<const short8*>(sB + (wn + in * 16 + l16) * 72 + ks * 32 + quad * 8);
#pragma unroll
      for (int im = 0; im < 4; ++im)
#pragma unroll
        for (int in = 0; in < 4; ++in)
          acc[im][in] = __builtin_amdgcn_mfma_f32_16x16x32_bf16(av[im], bv[in], acc[im][in], 0, 0, 0);
    }
    __syncthreads();
  }

  ushort_t* sC = sm;  // epilogue scratch [128][136] bf16
  if (MODE == 0) {
    const int section = n0 / 768;  // 0=Q 1=K 2=V
    const int obase = n0 - section * 768;
    if (section < 2) {
#pragma unroll
      for (int in = 0; in < 4; ++in) {
        int ol = wn + in * 16 + l16;
        float bv_ = bias[n0 + ol];
#pragma unroll
        for (int im = 0; im < 4; ++im)
#pragma unroll
          for (int r = 0; r < 4; ++r) {
            int row = wm + im * 16 + quad * 4 + r;
            sC[row * 136 + ol] = f2b(acc[im][in][r] + bv_);
          }
      }
      __syncthreads();
      ushort_t* dst = (ushort_t*)(section == 0 ? p0 : p1);
#pragma unroll
      for (int i = 0; i < 8; ++i) {
        int cid = i * 256 + tid;
        int row = cid >> 4, ch = cid & 15;
        *reinterpret_cast<uint4*>(dst + (size_t)(m0 + row) * 768 + obase + ch * 8) =
            *reinterpret_cast<const uint4*>(sC + row * 136 + ch * 8);
      }
    } else {
#pragma unroll
      for (int in = 0; in < 4; ++in) {
        int ol = wn + in * 16 + l16;
        float bv_ = bias[n0 + ol];
#pragma unroll
        for (int im = 0; im < 4; ++im)
#pragma unroll
          for (int r = 0; r < 4; ++r) {
            int mr = wm + im * 16 + quad * 4 + r;
            sC[ol * 136 + mr] = f2b(acc[im][in][r] + bv_);
          }
      }
      __syncthreads();
      ushort_t* dst = (ushort_t*)p2;
#pragma unroll
      for (int i = 0; i < 8; ++i) {
        int cid = i * 256 + tid;
        int o = cid >> 4, ch = cid & 15;
        *reinterpret_cast<uint4*>(dst + (size_t)(obase + o) * M + m0 + ch * 8) =
            *reinterpret_cast<const uint4*>(sC + o * 136 + ch * 8);
      }
    }
  } else {
#pragma unroll
    for (int in = 0; in < 4; ++in) {
      int ol = wn + in * 16 + l16;
      float bv_ = bias[n0 + ol];
#pragma unroll
      for (int im = 0; im < 4; ++im)
#pragma unroll
        for (int r = 0; r < 4; ++r) {
          int mr = wm + im * 16 + quad * 4 + r;
          sC[ol * 136 + mr] = f2b(acc[im][in][r] + bv_);
        }
    }
    __syncthreads();
    float* outp = (float*)p0;
    const float* resp = (const float*)p1;
#pragma unroll
    for (int i = 0; i < 16; ++i) {
      int cid = i * 256 + tid;
      int o = cid >> 5, ch = cid & 31;
      uint2 pk = *reinterpret_cast<const uint2*>(sC + o * 136 + ch * 4);
      size_t gidx;
      if (MODE == 1) {
        int b = m0 >> 12, f = (m0 >> 8) & 15, hw0 = m0 & 255;
        gidx = ((size_t)((b * 16 + f) * 768 + n0 + o)) * 256 + hw0 + ch * 4;
      } else {
        int b = m0 >> 10, t0 = m0 & 1023;
        gidx = ((size_t)(b * 768 + n0 + o)) * 1024 + t0 + ch * 4;
      }
      float4 rv = *reinterpret_cast<const float4*>(resp + gidx);
      float4 ov;
      ov.x = rv.x + b2f(pk.x & 0xffff);
      ov.y = rv.y + b2f(pk.x >> 16);
      ov.z = rv.z + b2f(pk.y & 0xffff);
      ov.w = rv.w + b2f(pk.y >> 16);
      *reinterpret_cast<float4*>(outp + gidx) = ov;
    }
  }
}

// ---------------------------------------------------------------------------
// MFMA flash attention over contiguous windows (shift=0).
// ---------------------------------------------------------------------------
template <int QW, int SW>
__global__ __launch_bounds__(256) void attn_mfma_kernel(
    const ushort_t* __restrict__ Qt, const ushort_t* __restrict__ Kt,
    const ushort_t* __restrict__ Vc, ushort_t* __restrict__ Ot,
    int TQb, int TSb, int Ms) {
  __shared__ ushort_t sK[128 * 72];   // K (stride 72) / V (stride 136) / Q staging
  __shared__ ushort_t sP[64 * 136];   // P bf16 / O bounce
  const int tid = threadIdx.x;
  const int lane = tid & 63, wave = tid >> 6;
  const int quad = lane >> 4, l16 = lane & 15;
  const int NQT = QW / 64;
  const int bx = blockIdx.x;
  const int qt = bx % NQT;
  const int win = (bx / NQT) & 3;
  const int h = (bx / (NQT * 4)) % 12;
  const int b = bx / (NQT * 48);
  const int hc = h * 64;
  const int nq0 = b * TQb + win * QW + qt * 64;
  const int ns_base = b * TSb + win * SW;

  // ---- stage Q (64 x 64) into sK (stride 72), scaled by 0.125
#pragma unroll
  for (int i = 0; i < 2; ++i) {
    int c = i * 256 + tid;
    int row = c >> 3, cc = c & 7;
    uint4 raw = *reinterpret_cast<const uint4*>(Qt + (size_t)(nq0 + row) * 768 + hc + cc * 8);
    unsigned int* rp = reinterpret_cast<unsigned int*>(&raw);
    uint4 out;
    unsigned int* op = reinterpret_cast<unsigned int*>(&out);
#pragma unroll
    for (int j = 0; j < 4; ++j) {
      unsigned int lo = (unsigned int)f2b(0.125f * b2f(rp[j] & 0xffff));
      unsigned int hi = (unsigned int)f2b(0.125f * b2f(rp[j] >> 16));
      op[j] = lo | (hi << 16);
    }
    *reinterpret_cast<uint4*>(sK + row * 72 + cc * 8) = out;
  }
  __syncthreads();
  short8 qf[2];
#pragma unroll
  for (int ks = 0; ks < 2; ++ks)
    qf[ks] = *reinterpret_cast<const short8*>(sK + (wave * 16 + l16) * 72 + ks * 32 + quad * 8);

  float mr[4], lr[4];
  f32x4 on[4];
#pragma unroll
  for (int r = 0; r < 4; ++r) { mr[r] = -1e30f; lr[r] = 0.f; }
#pragma unroll
  for (int nc = 0; nc < 4; ++nc) on[nc] = (f32x4){0.f, 0.f, 0.f, 0.f};

  for (int t = 0; t < SW / 128; ++t) {
    const int ns0 = ns_base + t * 128;
    __syncthreads();
    // ---- stage K tile [128 s][64 ch] token-major -> sK stride 72
#pragma unroll
    for (int i = 0; i < 4; ++i) {
      int c = i * 256 + tid;
      int row = c >> 3, cc = c & 7;
      *reinterpret_cast<uint4*>(sK + row * 72 + cc * 8) =
          *reinterpret_cast<const uint4*>(Kt + (size_t)(ns0 + row) * 768 + hc + cc * 8);
    }
    __syncthreads();
    // ---- S = Q K^T : 8 n-tiles x 2 k-steps
    f32x4 sf[8];
#pragma unroll
    for (int nt = 0; nt < 8; ++nt) sf[nt] = (f32x4){0.f, 0.f, 0.f, 0.f};
#pragma unroll
    for (int ks = 0; ks < 2; ++ks) {
#pragma unroll
      for (int nt = 0; nt < 8; ++nt) {
        short8 kf = *reinterpret_cast<const short8*>(sK + (nt * 16 + l16) * 72 + ks * 32 + quad * 8);
        sf[nt] = __builtin_amdgcn_mfma_f32_16x16x32_bf16(qf[ks], kf, sf[nt], 0, 0, 0);
      }
    }
    // ---- online softmax (row = quad*4+r, cols spread over l16 x nt)
#pragma unroll
    for (int r = 0; r < 4; ++r) {
      float m_ = sf[0][r];
#pragma unroll
      for (int nt = 1; nt < 8; ++nt) m_ = fmaxf(m_, sf[nt][r]);
#pragma unroll
      for (int off = 1; off < 16; off <<= 1) m_ = fmaxf(m_, __shfl_xor(m_, off));
      float mnew = fmaxf(mr[r], m_);
      float al = __expf(mr[r] - mnew);
      float ls = 0.f;
      int prow = (wave * 16 + quad * 4 + r) * 136;
#pragma unroll
      for (int nt = 0; nt < 8; ++nt) {
        float p = __expf(sf[nt][r] - mnew);
        ls += p;
        sP[prow + nt * 16 + l16] = f2b(p);
      }
#pragma unroll
      for (int off = 1; off < 16; off <<= 1) ls += __shfl_xor(ls, off);
      lr[r] = lr[r] * al + ls;
      mr[r] = mnew;
#pragma unroll
      for (int nc = 0; nc < 4; ++nc) on[nc][r] *= al;
    }
    __syncthreads();
    // ---- stage V tile [64 ch][128 s] channel-major -> sK stride 136
#pragma unroll
    for (int i = 0; i < 4; ++i) {
      int c = i * 256 + tid;
      int ch = c >> 4, cc = c & 15;
      *reinterpret_cast<uint4*>(sK + ch * 136 + cc * 8) =
          *reinterpret_cast<const uint4*>(Vc + (size_t)(hc + ch) * Ms + ns0 + cc * 8);
    }
    __syncthreads();
    // ---- O += P V : 4 k-steps (s) x 4 n-tiles (ch)
#pragma unroll
    for (int ks = 0; ks < 4; ++ks) {
      short8 pf = *reinterpret_cast<const short8*>(sP + (wave * 16 + l16) * 136 + ks * 32 + quad * 8);
#pragma unroll
      for (int nc = 0; nc < 4; ++nc) {
        short8 vf = *reinterpret_cast<const short8*>(sK + (nc * 16 + l16) * 136 + ks * 32 + quad * 8);
        on[nc] = __builtin_amdgcn_mfma_f32_16x16x32_bf16(pf, vf, on[nc], 0, 0, 0);
      }
    }
  }
  // ---- finalize: O /= l, bounce through sP for coalesced writes
#pragma unroll
  for (int r = 0; r < 4; ++r) {
    float inv = 1.f / lr[r];
    int prow = (wave * 16 + quad * 4 + r) * 136;
#pragma unroll
    for (int nc = 0; nc < 4; ++nc)
      sP[prow + nc * 16 + l16] = f2b(on[nc][r] * inv);
  }
  __syncthreads();
#pragma unroll
  for (int i = 0; i < 2; ++i) {
    int c = i * 256 + tid;
    int row = c >> 3, cc = c & 7;
    *reinterpret_cast<uint4*>(Ot + (size_t)(nq0 + row) * 768 + hc + cc * 8) =
        *reinterpret_cast<const uint4*>(sP + row * 136 + cc * 8);
  }
}

// ---------------------------------------------------------------------------
extern "C" void kernel_launch(void* const* d_in, const int* in_sizes, int n_in,
                              void* d_out, int out_size, void* d_ws, size_t ws_size,
                              hipStream_t stream) {
  (void)in_sizes; (void)n_in; (void)out_size; (void)ws_size;
  const float* video = (const float*)d_in[0];
  const float* audio = (const float*)d_in[1];
  const float* vn_s = (const float*)d_in[2];
  const float* vn_b = (const float*)d_in[3];
  const float* an_s = (const float*)d_in[4];
  const float* an_b = (const float*)d_in[5];
  const float* vqkv_w = (const float*)d_in[6];
  const float* vqkv_b = (const float*)d_in[7];
  const float* aqkv_w = (const float*)d_in[8];
  const float* aqkv_b = (const float*)d_in[9];
  const float* vproj_w = (const float*)d_in[10];
  const float* vproj_b = (const float*)d_in[11];
  const float* aproj_w = (const float*)d_in[12];
  const float* aproj_b = (const float*)d_in[13];

  float* out_v = (float*)d_out;
  float* out_a = out_v + (size_t)4 * 16 * 768 * 16 * 16;

  char* ws = (char*)d_ws;
  size_t off = 0;
  auto carve = [&](size_t bytes) {
    char* p = ws + off;
    off += (bytes + 255) & ~(size_t)255;
    return p;
  };
  float* mu = (float*)carve(256 * 4);
  float* rs = (float*)carve(256 * 4);
  float* part = (float*)carve(2560 * 2 * 4);
  ushort_t* Xv = (ushort_t*)carve((size_t)16384 * 768 * 2);
  ushort_t* Xa = (ushort_t*)carve((size_t)4096 * 768 * 2);
  ushort_t* Wqv = (ushort_t*)carve((size_t)2304 * 768 * 2);
  ushort_t* Wqa = (ushort_t*)carve((size_t)2304 * 768 * 2);
  ushort_t* Wpv = (ushort_t*)carve((size_t)768 * 768 * 2);
  ushort_t* Wpa = (ushort_t*)carve((size_t)768 * 768 * 2);
  ushort_t* Qv = (ushort_t*)carve((size_t)16384 * 768 * 2);
  ushort_t* Kv = (ushort_t*)carve((size_t)16384 * 768 * 2);
  ushort_t* Vv = (ushort_t*)carve((size_t)16384 * 768 * 2);
  ushort_t* Qa = (ushort_t*)carve((size_t)4096 * 768 * 2);
  ushort_t* Ka = (ushort_t*)carve((size_t)4096 * 768 * 2);
  ushort_t* Va = (ushort_t*)carve((size_t)4096 * 768 * 2);
  ushort_t* Ov = Xv;  // alias: X no longer needed after QKV GEMM
  ushort_t* Oa = Xa;

  wcvt_kernel<<<1024, 256, 0, stream>>>(vqkv_w, aqkv_w, vproj_w, aproj_w, Wqv, Wqa, Wpv, Wpa);
  gn_partial_kernel<<<2560, 256, 0, stream>>>(video, audio, part);
  gn_final_kernel<<<1, 256, 0, stream>>>(part, mu, rs);
  norm_video_kernel<<<1536, 256, 0, stream>>>(video, mu, rs, vn_s, vn_b, Xv);
  norm_audio_kernel<<<384, 256, 0, stream>>>(audio, mu, rs, an_s, an_b, Xa);
  gemm_kernel<0><<<dim3(18, 128), 256, 0, stream>>>(Xv, Wqv, vqkv_b, Qv, Kv, Vv, 16384);
  gemm_kernel<0><<<dim3(18, 32), 256, 0, stream>>>(Xa, Wqa, aqkv_b, Qa, Ka, Va, 4096);
  // video queries attend audio windows: QW=1024, SW=256
  attn_mfma_kernel<1024, 256><<<3072, 256, 0, stream>>>(Qv, Ka, Va, Ov, 4096, 1024, 4096);
  // audio queries attend video windows: QW=256, SW=1024
  attn_mfma_kernel<256, 1024><<<768, 256, 0, stream>>>(Qa, Kv, Vv, Oa, 1024, 4096, 16384);
  gemm_kernel<1><<<dim3(6, 128), 256, 0, stream>>>(Ov, Wpv, vproj_b, (void*)out_v, (void*)video, nullptr, 16384);
  gemm_kernel<2><<<dim3(6, 32), 256, 0, stream>>>(Oa, Wpa, aproj_b, (void*)out_a, (void*)audio, nullptr, 4096);
}